// Round 1
// baseline (27343.768 us; speedup 1.0000x reference)
//
#include <hip/hip_runtime.h>
#include <hip/hip_bf16.h>
#include <hip/hip_fp16.h>

#define S_LEN 8192
#define LC 16
#define CE 64
#define CH 64
#define WE 128
#define NTAGS 50

using bf16 = __hip_bfloat16;
typedef unsigned int u32;
typedef unsigned long long u64;

__device__ __forceinline__ float bfbits2f(unsigned short u) {
    union { unsigned int i; float f; } v; v.i = ((unsigned int)u) << 16; return v.f;
}
__device__ __forceinline__ float sigm(float x) {
    return __builtin_amdgcn_rcpf(1.0f + __expf(-x));
}
__device__ __forceinline__ float tanh_fast(float x) {
    return 1.0f - 2.0f * __builtin_amdgcn_rcpf(__expf(2.0f * x) + 1.0f);
}

// dtype-generic accessors ----------------------------------------------------
template <bool BF>
__device__ __forceinline__ float ld1(const void* p, size_t i) {
    if constexpr (BF) return bfbits2f(((const unsigned short*)p)[i]);
    else              return ((const float*)p)[i];
}
template <bool BF>
__device__ __forceinline__ float4 ld4(const void* p, size_t i) {  // elems i..i+3
    if constexpr (BF) {
        const ushort4 s = *reinterpret_cast<const ushort4*>((const unsigned short*)p + i);
        return make_float4(bfbits2f(s.x), bfbits2f(s.y), bfbits2f(s.z), bfbits2f(s.w));
    } else {
        return *reinterpret_cast<const float4*>((const float*)p + i);
    }
}
template <bool BF>
__device__ __forceinline__ void st1(void* p, size_t i, float v) {
    if constexpr (BF) ((bf16*)p)[i] = __float2bfloat16(v);
    else              ((float*)p)[i] = v;
}

// f16-pair helpers for the recurrent matvec ---------------------------------
typedef _Float16 h2t __attribute__((ext_vector_type(2)));

__device__ __forceinline__ u32 pk2(float a, float b) {        // RTE pack
    __half2 h = __floats2half2_rn(a, b);
    u32 r; __builtin_memcpy(&r, &h, 4); return r;
}
__device__ __forceinline__ float fdot2u(u32 a, u32 b, float c) {
#if __has_builtin(__builtin_amdgcn_fdot2)
    h2t av, bv;
    __builtin_memcpy(&av, &a, 4);
    __builtin_memcpy(&bv, &b, 4);
    return __builtin_amdgcn_fdot2(av, bv, c, false);
#else
    __half2 ah, bh;
    __builtin_memcpy(&ah, &a, 4);
    __builtin_memcpy(&bh, &b, 4);
    c = fmaf(__half2float(ah.x), __half2float(bh.x), c);
    c = fmaf(__half2float(ah.y), __half2float(bh.y), c);
    return c;
#endif
}

// Same-XCD L2-scope 8B packet ops: sc0 bypasses L1 (stale-L1 hazard) but may
// hit the XCD-shared L2 -> ~220cy RT instead of agent-scope MALL ~700cy.
// Only valid when all communicating blocks share one XCD (elected quad).
__device__ __forceinline__ u64 ld_l2(const u64* p) {
    u64 v;
    asm volatile("global_load_dwordx2 %0, %1, off sc0\n\t"
                 "s_waitcnt vmcnt(0)"
                 : "=&v"(v) : "v"(p) : "memory");
    return v;
}
__device__ __forceinline__ void st_l2(u64* p, u64 v) {
    asm volatile("global_store_dwordx2 %0, %1, off sc0"
                 :: "v"(p), "v"(v) : "memory");
}
// Poll with watchdog: if sc0 visibility assumption is ever wrong, trip to the
// agent-scope path (sticky per lane) -> correct, never hangs.
__device__ __forceinline__ u64 poll_pkt(u64* p, u32 want, bool& fastb) {
    u64 pk;
    if (fastb) {
        int guard = 0;
        for (;;) {
            pk = ld_l2(p);
            if ((u32)(pk >> 32) == want) return pk;
            if (++guard > (1 << 15)) { fastb = false; break; }
        }
    }
    do {
        pk = __hip_atomic_load(p, __ATOMIC_RELAXED, __HIP_MEMORY_SCOPE_AGENT);
    } while ((u32)(pk >> 32) != want);
    return pk;
}

// ---------------------------------------------------------------------------
// Detector: classify float-tensor dtype from char_emb's first 256 ushorts.
// ---------------------------------------------------------------------------
__global__ void kdetect(const void* emb, u32* flag) {
    const int j = threadIdx.x;           // 64 lanes
    int s = 0;
    #pragma unroll
    for (int k = 0; k < 4; ++k) {
        const unsigned short u = ((const unsigned short*)emb)[j * 4 + k];
        const int e = (u >> 7) & 0xFF;
        s += (e >= 100 && e <= 133) ? 1 : 0;
    }
    #pragma unroll
    for (int off = 32; off >= 1; off >>= 1) s += __shfl_xor(s, off, 64);
    if (j == 0) *flag = (s >= 200) ? 1u : 0u;
}

// ---------------------------------------------------------------------------
// Kernel A: char LSTM. 8 words/block, 256 threads (thread j = gate row j).
// ---------------------------------------------------------------------------
template <bool BF>
__global__ __launch_bounds__(256, 2) void kchar(
        const u32* __restrict__ dtf,
        const int* __restrict__ char_idxs, const int* __restrict__ char_lens,
        const void* __restrict__ char_emb,
        const void* __restrict__ Wih, const void* __restrict__ Whh,
        const void* __restrict__ bih, const void* __restrict__ bhh,
        float* __restrict__ cfeat) {
    if ((*dtf != 0u) != BF) return;
    const int j = threadIdx.x;
    const int w0 = blockIdx.x * 8;

    __shared__ __align__(16) float emb_lds[128 * CE];     // 32 KB
    __shared__ __align__(16) float gates_lds[8 * 256];    // 8 KB
    __shared__ __align__(16) float h_lds[8 * CH];
    __shared__ __align__(16) float c_lds[8 * CH];
    __shared__ int cidx_lds[8 * LC];
    __shared__ int len_lds[8];

    {
        float4* emb4 = reinterpret_cast<float4*>(emb_lds);
        #pragma unroll
        for (int i = 0; i < 8; ++i) {
            const int c = i * 256 + j;
            emb4[c] = ld4<BF>(char_emb, (size_t)c * 4);
        }
    }
    if (j < 128) cidx_lds[j] = char_idxs[w0 * LC + j];
    if (j < 8)   len_lds[j]  = char_lens[w0 + j];
    h_lds[j] = 0.f; h_lds[j + 256] = 0.f;
    c_lds[j] = 0.f; c_lds[j + 256] = 0.f;

    float4 wih4[16], whh4[16];
    #pragma unroll
    for (int kc = 0; kc < 16; ++kc) {
        wih4[kc] = ld4<BF>(Wih, (size_t)j * CE + kc * 4);
        whh4[kc] = ld4<BF>(Whh, (size_t)j * CH + kc * 4);
    }
    const float bias = ld1<BF>(bih, j) + ld1<BF>(bhh, j);
    __syncthreads();

    for (int t = 0; t < LC; ++t) {
        for (int w = 0; w < 8; ++w) {
            const int ci = cidx_lds[w * LC + t];
            const float4* x4  = reinterpret_cast<const float4*>(emb_lds + ci * CE);
            const float4* hh4 = reinterpret_cast<const float4*>(h_lds + w * CH);
            float a0 = 0.f, a1 = 0.f, a2 = 0.f, a3 = 0.f;
            #pragma unroll
            for (int kc = 0; kc < 16; ++kc) {
                const float4 xv = x4[kc]; const float4 hv = hh4[kc];
                const float4 wi = wih4[kc]; const float4 wh = whh4[kc];
                a0 = fmaf(wi.x, xv.x, a0); a1 = fmaf(wi.y, xv.y, a1);
                a2 = fmaf(wi.z, xv.z, a2); a3 = fmaf(wi.w, xv.w, a3);
                a0 = fmaf(wh.x, hv.x, a0); a1 = fmaf(wh.y, hv.y, a1);
                a2 = fmaf(wh.z, hv.z, a2); a3 = fmaf(wh.w, hv.w, a3);
            }
            gates_lds[w * 256 + j] = bias + ((a0 + a1) + (a2 + a3));
        }
        __syncthreads();
        #pragma unroll
        for (int rep = 0; rep < 2; ++rep) {
            const int p = j + rep * 256;       // p = w*64 + u
            const int w = p >> 6, u = p & 63;
            const float ig = gates_lds[w * 256 + u];
            const float fg = gates_lds[w * 256 + 64 + u];
            const float gg = gates_lds[w * 256 + 128 + u];
            const float og = gates_lds[w * 256 + 192 + u];
            const float cn = sigm(fg) * c_lds[p] + sigm(ig) * tanh_fast(gg);
            const float hn = sigm(og) * tanh_fast(cn);
            c_lds[p] = cn; h_lds[p] = hn;
            if (t == len_lds[w] - 1)
                cfeat[(size_t)(w0 + w) * CH + u] = hn;
        }
        __syncthreads();
    }
}

// ---------------------------------------------------------------------------
// Kernel B: Gx ring chunk. 16 words/block.
// ---------------------------------------------------------------------------
template <bool BF>
__global__ __launch_bounds__(256) void kgx(
        const u32* __restrict__ dtf,
        int t0, const int* __restrict__ word_idxs, const float* __restrict__ cfeat,
        const void* __restrict__ wemb, const void* __restrict__ Wih,
        const void* __restrict__ bih, const void* __restrict__ bhh,
        float* __restrict__ Gxr) {
    if ((*dtf != 0u) != BF) return;
    const int j = threadIdx.x;
    const int wr0 = blockIdx.x * 16;       // ring row base
    const int w0g = t0 + wr0;              // global word base
    __shared__ __align__(16) float wx[16 * 192];
    __shared__ int widx[16];
    if (j < 16) widx[j] = word_idxs[w0g + j];
    __syncthreads();
    {
        const int w = j >> 4, ch = j & 15;
        const size_t eb = (size_t)widx[w] * WE + ch * 8;
        const float4 f0 = ld4<BF>(wemb, eb), f1 = ld4<BF>(wemb, eb + 4);
        float4* dst = reinterpret_cast<float4*>(wx + w * 192 + ch * 8);
        dst[0] = f0; dst[1] = f1;
        const float4 cf = *reinterpret_cast<const float4*>(
            cfeat + (size_t)(w0g + w) * CH + ch * 4);
        *reinterpret_cast<float4*>(wx + w * 192 + WE + ch * 4) = cf;
    }
    __syncthreads();

    for (int g = 0; g < 4; ++g) {
        const int r = g * 256 + j;
        float acc[16];
        #pragma unroll
        for (int w = 0; w < 16; ++w) acc[w] = 0.f;
        #pragma unroll 8
        for (int kc = 0; kc < 48; ++kc) {
            const float4 wv = ld4<BF>(Wih, (size_t)r * 192 + kc * 4);
            #pragma unroll
            for (int w = 0; w < 16; ++w) {
                const float4 xv = *reinterpret_cast<const float4*>(wx + w * 192 + kc * 4);
                acc[w] = fmaf(wv.x, xv.x, acc[w]);
                acc[w] = fmaf(wv.y, xv.y, acc[w]);
                acc[w] = fmaf(wv.z, xv.z, acc[w]);
                acc[w] = fmaf(wv.w, xv.w, acc[w]);
            }
        }
        const float bias = ld1<BF>(bih, r) + ld1<BF>(bhh, r);
        #pragma unroll
        for (int w = 0; w < 16; ++w)
            Gxr[(size_t)(wr0 + w) * 1024 + r] = acc[w] + bias;
    }
}

// ---------------------------------------------------------------------------
// Kernel C: word LSTM steps [t0, t1). Grid = 64 blocks x 512 threads; election
// picks 4 worker blocks on ONE XCD (epoch-tagged publishes; pure function of
// published array -> exactly 4 distinct workers, deadlock-free).
//
// R0 changes vs previous version (theory: per-step 3150cy is ~60% cross-CU
// packet latency through agent-scope atomics = MALL round trip):
//  * h-exchange packets now use plain 8B global ops with sc0 (L1-bypass,
//    L2-hit): same-XCD L2 RT ~220cy vs MALL ~700cy. Publisher dual-stores
//    (sc0 + agent atomic, same value -> benign); pollers watchdog-fallback
//    to agent loads, so a wrong cache model degrades instead of hanging.
//  * Whh matvec in f16 v_dot2_f32_f16 (f32 accum): halves FMA issue
//    (512->256cy/SIMD/step) and weight VGPRs (64 u32). Gate error ~1e-3,
//    output error ~5e-3 << bf16 output ULP (0.03125).
//  * 512 threads (8 waves), split-K=2: cheaper barriers, 8-load gate reduce.
// Worker block b owns hidden units [64b,64b+64). Thread j = (kq=j>>8, r=j&255)
// holds Whh row ((r>>6)*256+b*64+(r&63)) cols [128kq,128kq+128) as 64 f16
// pairs. Per step: 192 lanes spin on tagged u64 packets -> pack f16 pairs to
// LDS -> barrier -> half-row dot2 matvec (+gx folded into kq==0 partials) ->
// barrier -> lanes j<64 sum 2 partials/gate, gate math, publish packet +
// local f16 h pair.
// ---------------------------------------------------------------------------
template <bool BF>
__global__ __launch_bounds__(512, 2) void kwlstm(
        const u32* __restrict__ dtf,
        int t0, int t1, int epoch, const void* __restrict__ whh,
        const float* __restrict__ Gxr,
        float* __restrict__ hallr, u64* hgx2, float* csave, u32* xccpub) {
    if ((*dtf != 0u) != BF) return;
    const int j = threadIdx.x;

    __shared__ int role_s;
    __shared__ int fast_s;
    // ---- same-XCD election (epoch-tagged) ----
    const u32 etag = 0xB0u + ((u32)epoch & 0xFu);
    if (j == 0) {
        const u32 xcc = __builtin_amdgcn_s_getreg(6164) & 0xFu;  // hwreg(XCC_ID,0,4)
        __hip_atomic_store(&xccpub[blockIdx.x], (etag << 24) | xcc,
                           __ATOMIC_RELAXED, __HIP_MEMORY_SCOPE_AGENT);
    }
    if (j < 64) {
        u32 v;
        do {
            v = __hip_atomic_load(&xccpub[j], __ATOMIC_RELAXED,
                                  __HIP_MEMORY_SCOPE_AGENT);
        } while ((v >> 24) != etag);
        const u32 v0 = __shfl(v, 0, 64);
        const u64 mask = __ballot((v & 0xFu) == (v0 & 0xFu));
        const int myb = blockIdx.x;
        int role = -1, fast = 0;
        if (__popcll(mask) >= 4) {
            fast = 1;                    // 4 workers share one XCD -> L2 path ok
            if ((mask >> myb) & 1ull) {
                const int rank = __popcll(mask & ((1ull << myb) - 1ull));
                if (rank < 4) role = rank;
            }
        } else {
            if (myb < 4) role = myb;     // fallback: cross-XCD, agent-scope path
        }
        if (j == 0) { role_s = role; fast_s = fast; }
    }
    __syncthreads();
    const int b = role_s;
    if (b < 0) return;
    bool fastb = (fast_s != 0);

    const int r  = j & 255;            // gate-row within block (g*64+u)
    const int kq = j >> 8;             // K half 0..1
    const int R  = ((r >> 6) << 8) + b * 64 + (r & 63);   // global gate-row

    __shared__ __align__(16) u32  h2[128];     // 256 h values as f16 pairs
    __shared__ __align__(16) float part[512];

    // Whh row half as 64 f16-pair dwords (RTE), resident in VGPRs.
    u32 wv2[64];
    #pragma unroll
    for (int kc = 0; kc < 32; ++kc) {
        const float4 w = ld4<BF>(whh, (size_t)R * 256 + kq * 128 + kc * 4);
        wv2[2 * kc]     = pk2(w.x, w.y);
        wv2[2 * kc + 1] = pk2(w.z, w.w);
    }

    if (j < 128) h2[j] = 0u;
    float c_reg = 0.f;
    if (t0 > 0 && j < 64) c_reg = csave[b * 64 + j];

    // 2-deep Gx pipeline (held by kq==0 threads, i.e. j<256)
    float gxA = (j < 256) ? Gxr[(size_t)0 * 1024 + R] : 0.f;              // t0
    float gxB = (j < 256 && t0 + 1 < t1) ? Gxr[(size_t)1 * 1024 + R] : 0.f;
    __syncthreads();

    for (int t = t0; t < t1; ++t) {
        if (t > 0) {
            if (t == t0) {                      // chunk start: gather all 256
                if (j < 256) {
                    const u64 pk = poll_pkt(&hgx2[(size_t)(t & 1) * 256 + j],
                                            (u32)t, fastb);
                    const float hv = __uint_as_float((u32)pk);
                    const float ho = __shfl_xor(hv, 1, 64);
                    if (!(j & 1)) h2[j >> 1] = pk2(hv, ho);
                }
            } else {                            // steady state: 192 remote only
                if (j < 192) {
                    const int gu = j + (j >= b * 64 ? 64 : 0);
                    const u64 pk = poll_pkt(&hgx2[(size_t)(t & 1) * 256 + gu],
                                            (u32)t, fastb);
                    const float hv = __uint_as_float((u32)pk);
                    const float ho = __shfl_xor(hv, 1, 64);
                    if (!(j & 1)) h2[gu >> 1] = pk2(hv, ho);
                }
            }
        }
        __syncthreads();                               // A: h2 ready
        float gxN = 0.f;                               // prefetch Gx[t+2]
        if (j < 256 && t + 2 < t1)
            gxN = Gxr[(size_t)(t + 2 - t0) * 1024 + R];
        float a0 = 0.f, a1 = 0.f, a2 = 0.f, a3 = 0.f;
        const uint4* h4 = reinterpret_cast<const uint4*>(h2 + kq * 64);
        #pragma unroll
        for (int kc = 0; kc < 16; ++kc) {
            const uint4 hv = h4[kc];               // wave-uniform broadcast
            a0 = fdot2u(wv2[4 * kc + 0], hv.x, a0);
            a1 = fdot2u(wv2[4 * kc + 1], hv.y, a1);
            a2 = fdot2u(wv2[4 * kc + 2], hv.z, a2);
            a3 = fdot2u(wv2[4 * kc + 3], hv.w, a3);
        }
        part[j] = ((a0 + a1) + (a2 + a3)) + (kq == 0 ? gxA : 0.f);
        __syncthreads();                               // B: partials ready
        if (j < 64) {
            const float ig = part[j]       + part[j + 256];
            const float fg = part[j + 64]  + part[j + 320];
            const float gg = part[j + 128] + part[j + 384];
            const float og = part[j + 192] + part[j + 448];
            const float cn = sigm(fg) * c_reg + sigm(ig) * tanh_fast(gg);
            c_reg = cn;
            const float hn = sigm(og) * tanh_fast(cn);
            const u64 pk = ((u64)(u32)(t + 1) << 32) | (u64)__float_as_uint(hn);
            u64* pp = &hgx2[(size_t)((t + 1) & 1) * 256 + b * 64 + j];
            if (fastb) st_l2(pp, pk);      // fast L2-visible copy first
            __hip_atomic_store(pp, pk, __ATOMIC_RELAXED,
                               __HIP_MEMORY_SCOPE_AGENT);  // same bits: benign
            const float ho = __shfl_xor(hn, 1, 64);
            if (!(j & 1)) h2[(b * 64 + j) >> 1] = pk2(hn, ho);  // local slice
            hallr[(size_t)(t - t0) * 256 + b * 64 + j] = hn;
        }
        gxA = gxB; gxB = gxN;
    }
    if (j < 64) csave[b * 64 + j] = c_reg;
}

// ---------------------------------------------------------------------------
// Kernel D: logits + log_softmax. One wave per word.
// ---------------------------------------------------------------------------
template <bool BF>
__global__ __launch_bounds__(64) void ktag(
        const u32* __restrict__ dtf,
        int t0, const float* __restrict__ hallr, const void* __restrict__ tagW,
        const void* __restrict__ tagb, void* __restrict__ out) {
    if ((*dtf != 0u) != BF) return;
    const int tr = blockIdx.x, j = threadIdx.x;
    const int t = t0 + tr;
    __shared__ __align__(16) float4 h4[64];
    h4[j] = reinterpret_cast<const float4*>(hallr + (size_t)tr * 256)[j];
    __syncthreads();
    float logit = -1e30f;
    if (j < NTAGS) {
        float a0 = 0.f, a1 = 0.f, a2 = 0.f, a3 = 0.f;
        #pragma unroll
        for (int kc = 0; kc < 64; ++kc) {
            const float4 wvv = ld4<BF>(tagW, (size_t)j * 256 + kc * 4);
            const float4 hv = h4[kc];
            a0 = fmaf(wvv.x, hv.x, a0); a1 = fmaf(wvv.y, hv.y, a1);
            a2 = fmaf(wvv.z, hv.z, a2); a3 = fmaf(wvv.w, hv.w, a3);
        }
        logit = ld1<BF>(tagb, j) + ((a0 + a1) + (a2 + a3));
    }
    float m = logit;
    #pragma unroll
    for (int off = 32; off >= 1; off >>= 1) m = fmaxf(m, __shfl_xor(m, off, 64));
    const float e = (j < NTAGS) ? __expf(logit - m) : 0.f;
    float ssum = e;
    #pragma unroll
    for (int off = 32; off >= 1; off >>= 1) ssum += __shfl_xor(ssum, off, 64);
    if (j < NTAGS)
        st1<BF>(out, (size_t)t * NTAGS + j, logit - m - __logf(ssum));
}

// ---------------------------------------------------------------------------
extern "C" void kernel_launch(void* const* d_in, const int* in_sizes, int n_in,
                              void* d_out, int out_size, void* d_ws, size_t ws_size,
                              hipStream_t stream) {
    const int*  word_idxs = (const int*)d_in[0];
    const int*  char_idxs = (const int*)d_in[1];
    const int*  char_lens = (const int*)d_in[2];
    const void* char_emb  = d_in[3];
    const void* char_Wih  = d_in[4];
    const void* char_Whh  = d_in[5];
    const void* char_bih  = d_in[6];
    const void* char_bhh  = d_in[7];
    const void* word_emb  = d_in[8];
    const void* word_Wih  = d_in[9];
    const void* word_Whh  = d_in[10];
    const void* word_bih  = d_in[11];
    const void* word_bhh  = d_in[12];
    const void* tag_W     = d_in[13];
    const void* tag_b     = d_in[14];

    // ws layout:
    //   [0,64)        dtflag u32
    //   [64,4160)     hgx2 u64[2][256]
    //   [4224,5248)   csave f32[256]
    //   [5248,5504)   xccpub u32[64]
    //   [8192,+2MB)   cfeat f32[8192*64]
    //   [ring0,...)   Gx ring f32[CT*1024] + hall ring f32[CT*256]
    char* ws = (char*)d_ws;
    u32*   dtf    = (u32*)(ws);
    u64*   hgx2   = (u64*)(ws + 64);
    float* csave  = (float*)(ws + 4224);
    u32*   xccpub = (u32*)(ws + 5248);
    float* cfeat  = (float*)(ws + 8192);
    const size_t ring0 = 8192 + (size_t)S_LEN * CH * 4;

    int NC = 256;
    const int ncs[9] = {1, 2, 4, 8, 16, 32, 64, 128, 256};
    for (int i = 0; i < 9; ++i) {
        const int ct = S_LEN / ncs[i];
        if (ring0 + (size_t)ct * 5120 <= ws_size) { NC = ncs[i]; break; }
    }
    const int CT = S_LEN / NC;
    float* Gxr   = (float*)(ws + ring0);
    float* hallr = (float*)(ws + ring0 + (size_t)CT * 4096);

    hipLaunchKernelGGL(kdetect, dim3(1), dim3(64), 0, stream, char_emb, dtf);
    hipLaunchKernelGGL(kchar<true>,  dim3(S_LEN / 8), dim3(256), 0, stream,
                       dtf, char_idxs, char_lens, char_emb, char_Wih, char_Whh,
                       char_bih, char_bhh, cfeat);
    hipLaunchKernelGGL(kchar<false>, dim3(S_LEN / 8), dim3(256), 0, stream,
                       dtf, char_idxs, char_lens, char_emb, char_Wih, char_Whh,
                       char_bih, char_bhh, cfeat);
    for (int c = 0; c < NC; ++c) {
        const int t0 = c * CT;
        hipLaunchKernelGGL(kgx<true>,  dim3(CT / 16), dim3(256), 0, stream,
                           dtf, t0, word_idxs, cfeat, word_emb, word_Wih,
                           word_bih, word_bhh, Gxr);
        hipLaunchKernelGGL(kgx<false>, dim3(CT / 16), dim3(256), 0, stream,
                           dtf, t0, word_idxs, cfeat, word_emb, word_Wih,
                           word_bih, word_bhh, Gxr);
        hipLaunchKernelGGL(kwlstm<true>,  dim3(64), dim3(512), 0, stream,
                           dtf, t0, t0 + CT, c, word_Whh, Gxr, hallr, hgx2, csave, xccpub);
        hipLaunchKernelGGL(kwlstm<false>, dim3(64), dim3(512), 0, stream,
                           dtf, t0, t0 + CT, c, word_Whh, Gxr, hallr, hgx2, csave, xccpub);
        hipLaunchKernelGGL(ktag<true>,  dim3(CT), dim3(64), 0, stream,
                           dtf, t0, hallr, tag_W, tag_b, d_out);
        hipLaunchKernelGGL(ktag<false>, dim3(CT), dim3(64), 0, stream,
                           dtf, t0, hallr, tag_W, tag_b, d_out);
    }
}

// Round 2
// 15325.035 us; speedup vs baseline: 1.7843x; 1.7843x over previous
//
#include <hip/hip_runtime.h>
#include <hip/hip_bf16.h>
#include <hip/hip_fp16.h>

#define S_LEN 8192
#define LC 16
#define CE 64
#define CH 64
#define WE 128
#define NTAGS 50

using bf16 = __hip_bfloat16;
typedef unsigned int u32;
typedef unsigned long long u64;

__device__ __forceinline__ float bfbits2f(unsigned short u) {
    union { unsigned int i; float f; } v; v.i = ((unsigned int)u) << 16; return v.f;
}
__device__ __forceinline__ float sigm(float x) {
    return __builtin_amdgcn_rcpf(1.0f + __expf(-x));
}
__device__ __forceinline__ float tanh_fast(float x) {
    return 1.0f - 2.0f * __builtin_amdgcn_rcpf(__expf(2.0f * x) + 1.0f);
}

// dtype-generic accessors ----------------------------------------------------
template <bool BF>
__device__ __forceinline__ float ld1(const void* p, size_t i) {
    if constexpr (BF) return bfbits2f(((const unsigned short*)p)[i]);
    else              return ((const float*)p)[i];
}
template <bool BF>
__device__ __forceinline__ float4 ld4(const void* p, size_t i) {  // elems i..i+3
    if constexpr (BF) {
        const ushort4 s = *reinterpret_cast<const ushort4*>((const unsigned short*)p + i);
        return make_float4(bfbits2f(s.x), bfbits2f(s.y), bfbits2f(s.z), bfbits2f(s.w));
    } else {
        return *reinterpret_cast<const float4*>((const float*)p + i);
    }
}
template <bool BF>
__device__ __forceinline__ void st1(void* p, size_t i, float v) {
    if constexpr (BF) ((bf16*)p)[i] = __float2bfloat16(v);
    else              ((float*)p)[i] = v;
}

// f16-pair helpers for the recurrent matvec (HW-validated in R1: absmax ok) --
typedef _Float16 h2t __attribute__((ext_vector_type(2)));

__device__ __forceinline__ u32 pk2(float a, float b) {        // RTE pack
    __half2 h = __floats2half2_rn(a, b);
    u32 r; __builtin_memcpy(&r, &h, 4); return r;
}
__device__ __forceinline__ float fdot2u(u32 a, u32 b, float c) {
#if __has_builtin(__builtin_amdgcn_fdot2)
    h2t av, bv;
    __builtin_memcpy(&av, &a, 4);
    __builtin_memcpy(&bv, &b, 4);
    return __builtin_amdgcn_fdot2(av, bv, c, false);
#else
    __half2 ah, bh;
    __builtin_memcpy(&ah, &a, 4);
    __builtin_memcpy(&bh, &b, 4);
    c = fmaf(__half2float(ah.x), __half2float(bh.x), c);
    c = fmaf(__half2float(ah.y), __half2float(bh.y), c);
    return c;
#endif
}

// ---------------------------------------------------------------------------
// Detector: classify float-tensor dtype from char_emb's first 256 ushorts.
// Also bumps the workspace generation counter (election tag freshness).
// ---------------------------------------------------------------------------
__global__ void kdetect(const void* emb, u32* flag, u32* gen) {
    const int j = threadIdx.x;           // 64 lanes
    int s = 0;
    #pragma unroll
    for (int k = 0; k < 4; ++k) {
        const unsigned short u = ((const unsigned short*)emb)[j * 4 + k];
        const int e = (u >> 7) & 0xFF;
        s += (e >= 100 && e <= 133) ? 1 : 0;
    }
    #pragma unroll
    for (int off = 32; off >= 1; off >>= 1) s += __shfl_xor(s, off, 64);
    if (j == 0) { *flag = (s >= 200) ? 1u : 0u; *gen = *gen + 1u; }
}

// ---------------------------------------------------------------------------
// Kernel A: char LSTM. 8 words/block, 256 threads (thread j = gate row j).
// ---------------------------------------------------------------------------
template <bool BF>
__global__ __launch_bounds__(256, 2) void kchar(
        const u32* __restrict__ dtf,
        const int* __restrict__ char_idxs, const int* __restrict__ char_lens,
        const void* __restrict__ char_emb,
        const void* __restrict__ Wih, const void* __restrict__ Whh,
        const void* __restrict__ bih, const void* __restrict__ bhh,
        float* __restrict__ cfeat) {
    if ((*dtf != 0u) != BF) return;
    const int j = threadIdx.x;
    const int w0 = blockIdx.x * 8;

    __shared__ __align__(16) float emb_lds[128 * CE];     // 32 KB
    __shared__ __align__(16) float gates_lds[8 * 256];    // 8 KB
    __shared__ __align__(16) float h_lds[8 * CH];
    __shared__ __align__(16) float c_lds[8 * CH];
    __shared__ int cidx_lds[8 * LC];
    __shared__ int len_lds[8];

    {
        float4* emb4 = reinterpret_cast<float4*>(emb_lds);
        #pragma unroll
        for (int i = 0; i < 8; ++i) {
            const int c = i * 256 + j;
            emb4[c] = ld4<BF>(char_emb, (size_t)c * 4);
        }
    }
    if (j < 128) cidx_lds[j] = char_idxs[w0 * LC + j];
    if (j < 8)   len_lds[j]  = char_lens[w0 + j];
    h_lds[j] = 0.f; h_lds[j + 256] = 0.f;
    c_lds[j] = 0.f; c_lds[j + 256] = 0.f;

    float4 wih4[16], whh4[16];
    #pragma unroll
    for (int kc = 0; kc < 16; ++kc) {
        wih4[kc] = ld4<BF>(Wih, (size_t)j * CE + kc * 4);
        whh4[kc] = ld4<BF>(Whh, (size_t)j * CH + kc * 4);
    }
    const float bias = ld1<BF>(bih, j) + ld1<BF>(bhh, j);
    __syncthreads();

    for (int t = 0; t < LC; ++t) {
        for (int w = 0; w < 8; ++w) {
            const int ci = cidx_lds[w * LC + t];
            const float4* x4  = reinterpret_cast<const float4*>(emb_lds + ci * CE);
            const float4* hh4 = reinterpret_cast<const float4*>(h_lds + w * CH);
            float a0 = 0.f, a1 = 0.f, a2 = 0.f, a3 = 0.f;
            #pragma unroll
            for (int kc = 0; kc < 16; ++kc) {
                const float4 xv = x4[kc]; const float4 hv = hh4[kc];
                const float4 wi = wih4[kc]; const float4 wh = whh4[kc];
                a0 = fmaf(wi.x, xv.x, a0); a1 = fmaf(wi.y, xv.y, a1);
                a2 = fmaf(wi.z, xv.z, a2); a3 = fmaf(wi.w, xv.w, a3);
                a0 = fmaf(wh.x, hv.x, a0); a1 = fmaf(wh.y, hv.y, a1);
                a2 = fmaf(wh.z, hv.z, a2); a3 = fmaf(wh.w, hv.w, a3);
            }
            gates_lds[w * 256 + j] = bias + ((a0 + a1) + (a2 + a3));
        }
        __syncthreads();
        #pragma unroll
        for (int rep = 0; rep < 2; ++rep) {
            const int p = j + rep * 256;       // p = w*64 + u
            const int w = p >> 6, u = p & 63;
            const float ig = gates_lds[w * 256 + u];
            const float fg = gates_lds[w * 256 + 64 + u];
            const float gg = gates_lds[w * 256 + 128 + u];
            const float og = gates_lds[w * 256 + 192 + u];
            const float cn = sigm(fg) * c_lds[p] + sigm(ig) * tanh_fast(gg);
            const float hn = sigm(og) * tanh_fast(cn);
            c_lds[p] = cn; h_lds[p] = hn;
            if (t == len_lds[w] - 1)
                cfeat[(size_t)(w0 + w) * CH + u] = hn;
        }
        __syncthreads();
    }
}

// ---------------------------------------------------------------------------
// Kernel B: Gx ring chunk. 16 words/block.
// ---------------------------------------------------------------------------
template <bool BF>
__global__ __launch_bounds__(256) void kgx(
        const u32* __restrict__ dtf,
        int t0, const int* __restrict__ word_idxs, const float* __restrict__ cfeat,
        const void* __restrict__ wemb, const void* __restrict__ Wih,
        const void* __restrict__ bih, const void* __restrict__ bhh,
        float* __restrict__ Gxr) {
    if ((*dtf != 0u) != BF) return;
    const int j = threadIdx.x;
    const int wr0 = blockIdx.x * 16;       // ring row base
    const int w0g = t0 + wr0;              // global word base
    __shared__ __align__(16) float wx[16 * 192];
    __shared__ int widx[16];
    if (j < 16) widx[j] = word_idxs[w0g + j];
    __syncthreads();
    {
        const int w = j >> 4, ch = j & 15;
        const size_t eb = (size_t)widx[w] * WE + ch * 8;
        const float4 f0 = ld4<BF>(wemb, eb), f1 = ld4<BF>(wemb, eb + 4);
        float4* dst = reinterpret_cast<float4*>(wx + w * 192 + ch * 8);
        dst[0] = f0; dst[1] = f1;
        const float4 cf = *reinterpret_cast<const float4*>(
            cfeat + (size_t)(w0g + w) * CH + ch * 4);
        *reinterpret_cast<float4*>(wx + w * 192 + WE + ch * 4) = cf;
    }
    __syncthreads();

    for (int g = 0; g < 4; ++g) {
        const int r = g * 256 + j;
        float acc[16];
        #pragma unroll
        for (int w = 0; w < 16; ++w) acc[w] = 0.f;
        #pragma unroll 8
        for (int kc = 0; kc < 48; ++kc) {
            const float4 wv = ld4<BF>(Wih, (size_t)r * 192 + kc * 4);
            #pragma unroll
            for (int w = 0; w < 16; ++w) {
                const float4 xv = *reinterpret_cast<const float4*>(wx + w * 192 + kc * 4);
                acc[w] = fmaf(wv.x, xv.x, acc[w]);
                acc[w] = fmaf(wv.y, xv.y, acc[w]);
                acc[w] = fmaf(wv.z, xv.z, acc[w]);
                acc[w] = fmaf(wv.w, xv.w, acc[w]);
            }
        }
        const float bias = ld1<BF>(bih, r) + ld1<BF>(bhh, r);
        #pragma unroll
        for (int w = 0; w < 16; ++w)
            Gxr[(size_t)(wr0 + w) * 1024 + r] = acc[w] + bias;
    }
}

// ---------------------------------------------------------------------------
// Kernel C: word LSTM steps [t0, t1). Grid = 64 x 512; election picks 4
// worker blocks (same-XCD preferred). Agent-scope u64 tagged packets =
// the R0-proven comm protocol (sc0 experiment failed; reverted).
//
// New structure (one barrier/step, poll overlaps compute):
//   waves 0-3  = compute: lane l of wave w owns FULL Whh row
//                R = (l>>4)*256 + b*64 + w*16 + (l&15)  as 128 f16-pair
//                dwords in VGPRs. dot2 matvec (f16, f32-accum; HW-validated
//                R1) -> 4 gates of a unit sit in lanes {m,m+16,m+32,m+48}
//                of ONE wave -> gate math via 3 __shfl, no LDS reduce, no
//                second barrier. Lanes l<16 hold c, publish h(t+1).
//   waves 4-7  = poll: after barrier A they immediately poll step t+1's
//                remote packets while compute waves crunch step t ->
//                publish->observe latency overlaps local compute.
//   h2[2][128] = double-buffered f16-pair h (parity t&1) -> single barrier.
// ---------------------------------------------------------------------------
template <bool BF>
__global__ __launch_bounds__(512, 2) void kwlstm(
        const u32* __restrict__ dtf,
        int t0, int t1, int epoch, const void* __restrict__ whh,
        const float* __restrict__ Gxr,
        float* __restrict__ hallr, u64* hgx2, float* csave, u32* xccpub,
        const u32* __restrict__ genp) {
    if ((*dtf != 0u) != BF) return;
    const int j = threadIdx.x;

    __shared__ int role_s;
    // ---- same-XCD election (generation+epoch-tagged, agent scope) ----
    const u32 et = (((*genp) << 8) + (u32)epoch) & 0xFFFFFFu;
    if (j == 0) {
        const u32 xcc = __builtin_amdgcn_s_getreg(6164) & 0xFu;  // hwreg(XCC_ID,0,4)
        __hip_atomic_store(&xccpub[blockIdx.x], (et << 8) | xcc,
                           __ATOMIC_RELAXED, __HIP_MEMORY_SCOPE_AGENT);
    }
    if (j < 64) {
        u32 v;
        do {
            v = __hip_atomic_load(&xccpub[j], __ATOMIC_RELAXED,
                                  __HIP_MEMORY_SCOPE_AGENT);
        } while ((v >> 8) != et);
        const u32 v0 = __shfl(v, 0, 64);
        const u64 mask = __ballot((v & 0xFFu) == (v0 & 0xFFu));
        const int myb = blockIdx.x;
        int role = -1;
        if (__popcll(mask) >= 4) {
            if ((mask >> myb) & 1ull) {
                const int rank = __popcll(mask & ((1ull << myb) - 1ull));
                if (rank < 4) role = rank;
            }
        } else {
            if (myb < 4) role = myb;   // fallback: cross-XCD, still correct
        }
        if (j == 0) role_s = role;
    }
    __syncthreads();
    const int b = role_s;
    if (b < 0) return;

    const int wv_id   = j >> 6;            // wave 0..7
    const bool is_comp = (wv_id < 4);
    const int l = j & 63;
    const int m = l & 15;                  // unit-in-group
    const int g = l >> 4;                  // gate 0..3 (i,f,g,o)
    const int u = wv_id * 16 + m;          // unit within worker (compute waves)
    const int R = g * 256 + b * 64 + u;    // global gate row
    const int pj = j - 256;                // poll index (waves 4-7): 0..255

    __shared__ __align__(16) u32 h2[2][128];   // f16-pair h, parity-buffered

    // Whh full row as 128 f16-pair dwords, resident in VGPRs (compute waves).
    u32 wv2[128];
    if (is_comp) {
        #pragma unroll
        for (int kc = 0; kc < 64; ++kc) {
            const float4 w = ld4<BF>(whh, (size_t)R * 256 + kc * 4);
            wv2[2 * kc]     = pk2(w.x, w.y);
            wv2[2 * kc + 1] = pk2(w.z, w.w);
        }
    }
    if (j < 128) { h2[0][j] = 0u; h2[1][j] = 0u; }

    const bool is_hn = is_comp && (l < 16);
    float c_reg = 0.f;
    if (t0 > 0 && is_hn) c_reg = csave[b * 64 + u];

    // 2-deep Gx pipeline (compute lanes; row R of ring)
    float gxA = 0.f, gxB = 0.f;
    if (is_comp) {
        gxA = Gxr[(size_t)0 * 1024 + R];
        if (t0 + 1 < t1) gxB = Gxr[(size_t)1 * 1024 + R];
    }
    __syncthreads();   // h2 zero-init visible before any gather writes

    // chunk start (t0>0): hn lanes gather OWN 64 h(t0) (self-published last
    // chunk); poll waves will gather the 192 remote in the first loop iter.
    if (t0 > 0 && is_hn) {
        u64 pk;
        do {
            pk = __hip_atomic_load(&hgx2[(size_t)(t0 & 1) * 256 + b * 64 + u],
                                   __ATOMIC_RELAXED, __HIP_MEMORY_SCOPE_AGENT);
        } while ((u32)(pk >> 32) != (u32)t0);
        const float hv = __uint_as_float((u32)pk);
        const float ho = __shfl_xor(hv, 1, 64);
        if (!(m & 1)) h2[t0 & 1][(b * 64 + u) >> 1] = pk2(hv, ho);
    }

    for (int t = t0; t < t1; ++t) {
        // ---- poll phase: waves 4-6 fetch the 192 remote h(t) ----
        if (!is_comp && t > 0 && pj < 192) {
            const int gu = pj + (pj >= b * 64 ? 64 : 0);
            u64 pk;
            do {
                pk = __hip_atomic_load(&hgx2[(size_t)(t & 1) * 256 + gu],
                                       __ATOMIC_RELAXED, __HIP_MEMORY_SCOPE_AGENT);
            } while ((u32)(pk >> 32) != (u32)t);
            const float hv = __uint_as_float((u32)pk);
            const float ho = __shfl_xor(hv, 1, 64);
            if (!(pj & 1)) h2[t & 1][gu >> 1] = pk2(hv, ho);
        }
        __syncthreads();   // A: h2[t&1] complete (remote by pollers, local by
                           //    hn lanes at end of previous compute phase)

        if (is_comp) {
            float gxN = 0.f;                           // prefetch Gx[t+2]
            if (t + 2 < t1) gxN = Gxr[(size_t)(t + 2 - t0) * 1024 + R];

            const uint4* h4 = reinterpret_cast<const uint4*>(h2[t & 1]);
            float a0 = 0.f, a1 = 0.f, a2 = 0.f, a3 = 0.f;
            #pragma unroll
            for (int kc = 0; kc < 32; ++kc) {
                const uint4 hv = h4[kc];               // wave-uniform broadcast
                a0 = fdot2u(wv2[4 * kc + 0], hv.x, a0);
                a1 = fdot2u(wv2[4 * kc + 1], hv.y, a1);
                a2 = fdot2u(wv2[4 * kc + 2], hv.z, a2);
                a3 = fdot2u(wv2[4 * kc + 3], hv.w, a3);
            }
            const float gv = ((a0 + a1) + (a2 + a3)) + gxA;
            // activation: gate g==2 (cell candidate) uses tanh, others sigmoid
            const float act = (g == 2) ? tanh_fast(gv) : sigm(gv);
            const float a_f = __shfl(act, m + 16, 64);
            const float a_g = __shfl(act, m + 32, 64);
            const float a_o = __shfl(act, m + 48, 64);
            if (l < 16) {                              // act == sigm(i) here
                const float cn = a_f * c_reg + act * a_g;
                c_reg = cn;
                const float hn = a_o * tanh_fast(cn);
                // publish FIRST (critical path for remote workers)
                const u64 pk = ((u64)(u32)(t + 1) << 32) | (u64)__float_as_uint(hn);
                __hip_atomic_store(&hgx2[(size_t)((t + 1) & 1) * 256 + b * 64 + u],
                                   pk, __ATOMIC_RELAXED, __HIP_MEMORY_SCOPE_AGENT);
                const float ho = __shfl_xor(hn, 1, 64);
                if (!(m & 1)) h2[(t + 1) & 1][(b * 64 + u) >> 1] = pk2(hn, ho);
                hallr[(size_t)(t - t0) * 256 + b * 64 + u] = hn;
            }
            gxA = gxB; gxB = gxN;
        }
        // no second barrier: poll waves loop straight into polling t+1's
        // packets (parity (t+1)&1 -> no conflict with h2[t&1] being read),
        // overlapping the remote publish->observe latency with local compute.
    }
    if (is_hn) csave[b * 64 + u] = c_reg;
}

// ---------------------------------------------------------------------------
// Kernel D: logits + log_softmax. One wave per word.
// ---------------------------------------------------------------------------
template <bool BF>
__global__ __launch_bounds__(64) void ktag(
        const u32* __restrict__ dtf,
        int t0, const float* __restrict__ hallr, const void* __restrict__ tagW,
        const void* __restrict__ tagb, void* __restrict__ out) {
    if ((*dtf != 0u) != BF) return;
    const int tr = blockIdx.x, j = threadIdx.x;
    const int t = t0 + tr;
    __shared__ __align__(16) float4 h4[64];
    h4[j] = reinterpret_cast<const float4*>(hallr + (size_t)tr * 256)[j];
    __syncthreads();
    float logit = -1e30f;
    if (j < NTAGS) {
        float a0 = 0.f, a1 = 0.f, a2 = 0.f, a3 = 0.f;
        #pragma unroll
        for (int kc = 0; kc < 64; ++kc) {
            const float4 wvv = ld4<BF>(tagW, (size_t)j * 256 + kc * 4);
            const float4 hv = h4[kc];
            a0 = fmaf(wvv.x, hv.x, a0); a1 = fmaf(wvv.y, hv.y, a1);
            a2 = fmaf(wvv.z, hv.z, a2); a3 = fmaf(wvv.w, hv.w, a3);
        }
        logit = ld1<BF>(tagb, j) + ((a0 + a1) + (a2 + a3));
    }
    float m = logit;
    #pragma unroll
    for (int off = 32; off >= 1; off >>= 1) m = fmaxf(m, __shfl_xor(m, off, 64));
    const float e = (j < NTAGS) ? __expf(logit - m) : 0.f;
    float ssum = e;
    #pragma unroll
    for (int off = 32; off >= 1; off >>= 1) ssum += __shfl_xor(ssum, off, 64);
    if (j < NTAGS)
        st1<BF>(out, (size_t)t * NTAGS + j, logit - m - __logf(ssum));
}

// ---------------------------------------------------------------------------
extern "C" void kernel_launch(void* const* d_in, const int* in_sizes, int n_in,
                              void* d_out, int out_size, void* d_ws, size_t ws_size,
                              hipStream_t stream) {
    const int*  word_idxs = (const int*)d_in[0];
    const int*  char_idxs = (const int*)d_in[1];
    const int*  char_lens = (const int*)d_in[2];
    const void* char_emb  = d_in[3];
    const void* char_Wih  = d_in[4];
    const void* char_Whh  = d_in[5];
    const void* char_bih  = d_in[6];
    const void* char_bhh  = d_in[7];
    const void* word_emb  = d_in[8];
    const void* word_Wih  = d_in[9];
    const void* word_Whh  = d_in[10];
    const void* word_bih  = d_in[11];
    const void* word_bhh  = d_in[12];
    const void* tag_W     = d_in[13];
    const void* tag_b     = d_in[14];

    // ws layout:
    //   [0,64)        dtflag u32
    //   [64,4160)     hgx2 u64[2][256]
    //   [4224,5248)   csave f32[256]
    //   [5248,5504)   xccpub u32[64]
    //   [5504,5508)   gen u32 (persists across launches)
    //   [8192,+2MB)   cfeat f32[8192*64]
    //   [ring0,...)   Gx ring f32[CT*1024] + hall ring f32[CT*256]
    char* ws = (char*)d_ws;
    u32*   dtf    = (u32*)(ws);
    u64*   hgx2   = (u64*)(ws + 64);
    float* csave  = (float*)(ws + 4224);
    u32*   xccpub = (u32*)(ws + 5248);
    u32*   genp   = (u32*)(ws + 5504);
    float* cfeat  = (float*)(ws + 8192);
    const size_t ring0 = 8192 + (size_t)S_LEN * CH * 4;

    int NC = 256;
    const int ncs[9] = {1, 2, 4, 8, 16, 32, 64, 128, 256};
    for (int i = 0; i < 9; ++i) {
        const int ct = S_LEN / ncs[i];
        if (ring0 + (size_t)ct * 5120 <= ws_size) { NC = ncs[i]; break; }
    }
    const int CT = S_LEN / NC;
    float* Gxr   = (float*)(ws + ring0);
    float* hallr = (float*)(ws + ring0 + (size_t)CT * 4096);

    hipLaunchKernelGGL(kdetect, dim3(1), dim3(64), 0, stream, char_emb, dtf, genp);
    hipLaunchKernelGGL(kchar<true>,  dim3(S_LEN / 8), dim3(256), 0, stream,
                       dtf, char_idxs, char_lens, char_emb, char_Wih, char_Whh,
                       char_bih, char_bhh, cfeat);
    hipLaunchKernelGGL(kchar<false>, dim3(S_LEN / 8), dim3(256), 0, stream,
                       dtf, char_idxs, char_lens, char_emb, char_Wih, char_Whh,
                       char_bih, char_bhh, cfeat);
    for (int c = 0; c < NC; ++c) {
        const int t0 = c * CT;
        hipLaunchKernelGGL(kgx<true>,  dim3(CT / 16), dim3(256), 0, stream,
                           dtf, t0, word_idxs, cfeat, word_emb, word_Wih,
                           word_bih, word_bhh, Gxr);
        hipLaunchKernelGGL(kgx<false>, dim3(CT / 16), dim3(256), 0, stream,
                           dtf, t0, word_idxs, cfeat, word_emb, word_Wih,
                           word_bih, word_bhh, Gxr);
        hipLaunchKernelGGL(kwlstm<true>,  dim3(64), dim3(512), 0, stream,
                           dtf, t0, t0 + CT, c, word_Whh, Gxr, hallr, hgx2,
                           csave, xccpub, genp);
        hipLaunchKernelGGL(kwlstm<false>, dim3(64), dim3(512), 0, stream,
                           dtf, t0, t0 + CT, c, word_Whh, Gxr, hallr, hgx2,
                           csave, xccpub, genp);
        hipLaunchKernelGGL(ktag<true>,  dim3(CT), dim3(64), 0, stream,
                           dtf, t0, hallr, tag_W, tag_b, d_out);
        hipLaunchKernelGGL(ktag<false>, dim3(CT), dim3(64), 0, stream,
                           dtf, t0, hallr, tag_W, tag_b, d_out);
    }
}